// Round 5
// baseline (2952.498 us; speedup 1.0000x reference)
//
#include <hip/hip_runtime.h>
#include <hip/hip_bf16.h>

#define DIM 128
#define BM 32
#define BK 64

// deg[i] = 1.0 (self loop)
__global__ __launch_bounds__(256) void init_deg_kernel(float* __restrict__ deg, int n) {
    int i = blockIdx.x * blockDim.x + threadIdx.x;
    if (i < n) deg[i] = 1.0f;
}

// deg[col[e]] += 1   (col is int32)
__global__ __launch_bounds__(256) void deg_kernel(const int* __restrict__ col, float* __restrict__ deg, int E) {
    int e = blockIdx.x * blockDim.x + threadIdx.x;
    if (e < E) atomicAdd(&deg[col[e]], 1.0f);
}

// in-place deg -> deg^{-1/2}  (deg >= 1 always, no zero guard needed)
__global__ __launch_bounds__(256) void dinv_kernel(float* __restrict__ deg, int n) {
    int i = blockIdx.x * blockDim.x + threadIdx.x;
    if (i < n) deg[i] = 1.0f / sqrtf(deg[i]);
}

// WpT[j*DIM + i] = Wp[i][j] = sum_k Wg[i,k] * Wl[k,j]   (W' = W_gcn @ W_lin, stored transposed)
__global__ __launch_bounds__(128) void wp_kernel(const float* __restrict__ Wg,
                                                 const float* __restrict__ Wl,
                                                 float* __restrict__ WpT) {
    int i = blockIdx.x;      // output dim
    int j = threadIdx.x;     // x dim (k of the big GEMM)
    float s = 0.f;
    for (int k = 0; k < DIM; ++k)
        s = fmaf(Wg[i * DIM + k], Wl[k * DIM + j], s);
    WpT[j * DIM + i] = s;
}

// h_s[n,:] = dinv[n] * (x[n,:] @ Wp^T)   -- tiled GEMM, BM=32 rows/block, BK=64
__global__ __launch_bounds__(256) void gemm_hs_kernel(const float* __restrict__ x,
                                                      const float* __restrict__ WpT,
                                                      const float* __restrict__ dinv,
                                                      float* __restrict__ h) {
    __shared__ float xs[BK * BM];    // [k][r] transposed, 8 KB
    __shared__ float ws[BK * DIM];   // [k][j], 32 KB
    const int tid  = threadIdx.x;
    const int brow = blockIdx.x * BM;
    const int c4   = (tid & 31) * 4;   // col base (0..124)
    const int r4   = (tid >> 5) * 4;   // row base (0..28)

    float acc[4][4];
#pragma unroll
    for (int i = 0; i < 4; ++i)
#pragma unroll
        for (int j = 0; j < 4; ++j) acc[i][j] = 0.f;

    for (int k0 = 0; k0 < DIM; k0 += BK) {
        // stage x tile: 32 rows x 64 k (fp32) -> xs[k][r] (transposed)
        {
            const int row = tid >> 3;          // 0..31
            const int kq  = (tid & 7) * 8;     // 0..56
            const float* xp = x + (size_t)(brow + row) * DIM + k0 + kq;
            const float4 a0 = *(const float4*)(xp);
            const float4 a1 = *(const float4*)(xp + 4);
            xs[(kq + 0) * BM + row] = a0.x;
            xs[(kq + 1) * BM + row] = a0.y;
            xs[(kq + 2) * BM + row] = a0.z;
            xs[(kq + 3) * BM + row] = a0.w;
            xs[(kq + 4) * BM + row] = a1.x;
            xs[(kq + 5) * BM + row] = a1.y;
            xs[(kq + 6) * BM + row] = a1.z;
            xs[(kq + 7) * BM + row] = a1.w;
        }
        // stage W' tile: rows k0..k0+63 of WpT (fp32) -> ws, linear float4 copy
        {
            const float4* src = (const float4*)(WpT + (size_t)k0 * DIM);
            float4* dst = (float4*)ws;
#pragma unroll
            for (int t = 0; t < 8; ++t) dst[tid + t * 256] = src[tid + t * 256];
        }
        __syncthreads();

#pragma unroll 16
        for (int kk = 0; kk < BK; ++kk) {
            const float4 xv = *(const float4*)(xs + kk * BM + r4);   // broadcast within half-wave
            const float4 wv = *(const float4*)(ws + kk * DIM + c4);  // lane-consecutive 16B
            const float xr[4] = {xv.x, xv.y, xv.z, xv.w};
            const float wr[4] = {wv.x, wv.y, wv.z, wv.w};
#pragma unroll
            for (int i = 0; i < 4; ++i)
#pragma unroll
                for (int j = 0; j < 4; ++j)
                    acc[i][j] = fmaf(xr[i], wr[j], acc[i][j]);
        }
        __syncthreads();
    }

    // epilogue: scale by dinv[row], float4 store
#pragma unroll
    for (int i = 0; i < 4; ++i) {
        const int row = brow + r4 + i;
        const float dv = dinv[row];
        float4 o = make_float4(acc[i][0] * dv, acc[i][1] * dv, acc[i][2] * dv, acc[i][3] * dv);
        *(float4*)(h + (size_t)row * DIM + c4) = o;
    }
}

// acc[col[e],:] += h_s[row[e],:]   -- 32 lanes per edge, float4 gather + 4 scalar atomics
__global__ __launch_bounds__(256) void scatter_kernel(const int* __restrict__ src,
                                                      const int* __restrict__ dst,
                                                      const float* __restrict__ h,
                                                      float* __restrict__ acc, int E) {
    int g = blockIdx.x * blockDim.x + threadIdx.x;
    int e = g >> 5;
    if (e >= E) return;
    int lane = g & 31;
    int r = src[e];
    int c = dst[e];
    const float4 v = *(const float4*)(h + (size_t)r * DIM + lane * 4);
    float* a = acc + (size_t)c * DIM + lane * 4;
    atomicAdd(a + 0, v.x);
    atomicAdd(a + 1, v.y);
    atomicAdd(a + 2, v.z);
    atomicAdd(a + 3, v.w);
}

// out = dinv[node]*(acc + h_s) + b[col]   (h_s term = self loop) -- fp32 output
__global__ __launch_bounds__(256) void finalize_kernel(const float* __restrict__ acc,
                                                       const float* __restrict__ h,
                                                       const float* __restrict__ dinv,
                                                       const float* __restrict__ b,
                                                       float* __restrict__ out, int total4) {
    int i = blockIdx.x * blockDim.x + threadIdx.x;
    if (i >= total4) return;
    const int idx = i * 4;
    const int row = idx >> 7;
    const int col = idx & 127;
    const float dv = dinv[row];
    const float4 a  = *(const float4*)(acc + idx);
    const float4 hh = *(const float4*)(h + idx);
    float4 o;
    o.x = dv * (a.x + hh.x) + b[col + 0];
    o.y = dv * (a.y + hh.y) + b[col + 1];
    o.z = dv * (a.z + hh.z) + b[col + 2];
    o.w = dv * (a.w + hh.w) + b[col + 3];
    *(float4*)(out + idx) = o;
}

extern "C" void kernel_launch(void* const* d_in, const int* in_sizes, int n_in,
                              void* d_out, int out_size, void* d_ws, size_t ws_size,
                              hipStream_t stream) {
    const float* x  = (const float*)d_in[0];   // fp32 [N,128]
    const int*   ei = (const int*)d_in[1];     // int32 flat [2,E]
    const float* Wl = (const float*)d_in[2];   // fp32 [128,128]
    const float* Wg = (const float*)d_in[3];   // fp32 [128,128]
    const float* bg = (const float*)d_in[4];   // fp32 [128]

    const int N = in_sizes[0] / DIM;      // 100000
    const int E = in_sizes[1] / 2;        // 1600000
    const int* srcIdx = ei;               // edge_index[0] = row (source)
    const int* dstIdx = ei + E;           // edge_index[1] = col (target)

    // workspace layout (fp32)
    float* WpT = (float*)d_ws;                                   // 128*128*4 = 64 KB
    float* deg = (float*)((char*)d_ws + 65536);                  // N*4
    float* h   = (float*)((char*)d_ws + (1 << 20));              // N*DIM*4 = 51.2 MB
    float* acc = h + (size_t)N * DIM;                            // N*DIM*4 = 51.2 MB
    const size_t needed = (size_t)(1 << 20) + 2ull * N * DIM * 4;
    if (ws_size < needed) return;  // insufficient workspace: fail loudly

    hipMemsetAsync(acc, 0, (size_t)N * DIM * sizeof(float), stream);

    init_deg_kernel<<<(N + 255) / 256, 256, 0, stream>>>(deg, N);
    deg_kernel<<<(E + 255) / 256, 256, 0, stream>>>(dstIdx, deg, E);
    dinv_kernel<<<(N + 255) / 256, 256, 0, stream>>>(deg, N);
    wp_kernel<<<DIM, DIM, 0, stream>>>(Wg, Wl, WpT);
    gemm_hs_kernel<<<N / BM, 256, 0, stream>>>(x, WpT, deg, h);
    {
        long long total = (long long)E * 32;
        scatter_kernel<<<(int)((total + 255) / 256), 256, 0, stream>>>(srcIdx, dstIdx, h, acc, E);
    }
    {
        int total4 = N * DIM / 4;
        finalize_kernel<<<(total4 + 255) / 256, 256, 0, stream>>>(acc, h, deg, bg,
                                                                  (float*)d_out, total4);
    }
}

// Round 6
// 453.378 us; speedup vs baseline: 6.5122x; 6.5122x over previous
//
#include <hip/hip_runtime.h>
#include <hip/hip_bf16.h>

#define DIM 128
#define BM 32
#define BK 64

// ---------- degree histogram (int) ----------
__global__ __launch_bounds__(256) void degi_kernel(const int* __restrict__ dst, int* __restrict__ degi, int E) {
    int e = blockIdx.x * blockDim.x + threadIdx.x;
    if (e < E) atomicAdd(&degi[dst[e]], 1);
}

// dinv[i] = (deg_in + 1)^{-1/2}  (self loop included)
__global__ __launch_bounds__(256) void dinv_kernel(const int* __restrict__ degi, float* __restrict__ dinv, int n) {
    int i = blockIdx.x * blockDim.x + threadIdx.x;
    if (i < n) dinv[i] = 1.0f / sqrtf((float)(degi[i] + 1));
}

// ---------- 3-kernel exclusive scan over degi -> offs ----------
__global__ __launch_bounds__(256) void scan1_kernel(const int* __restrict__ deg, int* __restrict__ offs,
                                                    int* __restrict__ blksum, int n) {
    __shared__ int lds[256];
    const int t = threadIdx.x;
    const int base = blockIdx.x * 1024 + t * 4;
    int v0 = (base + 0 < n) ? deg[base + 0] : 0;
    int v1 = (base + 1 < n) ? deg[base + 1] : 0;
    int v2 = (base + 2 < n) ? deg[base + 2] : 0;
    int v3 = (base + 3 < n) ? deg[base + 3] : 0;
    const int tot = v0 + v1 + v2 + v3;
    lds[t] = tot;
    __syncthreads();
    for (int off = 1; off < 256; off <<= 1) {          // Hillis-Steele inclusive
        int val = (t >= off) ? lds[t - off] : 0;
        __syncthreads();
        lds[t] += val;
        __syncthreads();
    }
    const int excl = lds[t] - tot;
    if (base + 0 < n) offs[base + 0] = excl;
    if (base + 1 < n) offs[base + 1] = excl + v0;
    if (base + 2 < n) offs[base + 2] = excl + v0 + v1;
    if (base + 3 < n) offs[base + 3] = excl + v0 + v1 + v2;
    if (t == 255) blksum[blockIdx.x] = lds[255];
}

__global__ __launch_bounds__(128) void scan2_kernel(int* __restrict__ blksum, int nb) {
    __shared__ int lds[128];
    const int t = threadIdx.x;
    const int v = (t < nb) ? blksum[t] : 0;
    lds[t] = v;
    __syncthreads();
    for (int off = 1; off < 128; off <<= 1) {
        int val = (t >= off) ? lds[t - off] : 0;
        __syncthreads();
        lds[t] += val;
        __syncthreads();
    }
    if (t < nb) blksum[t] = lds[t] - v;                // exclusive
}

__global__ __launch_bounds__(256) void scan3_kernel(int* __restrict__ offs, const int* __restrict__ blksum, int n) {
    int i = blockIdx.x * 256 + threadIdx.x;
    if (i < n) offs[i] += blksum[i >> 10];
}

// ---------- CSR fill ----------
__global__ __launch_bounds__(256) void fill_kernel(const int* __restrict__ src, const int* __restrict__ dst,
                                                   const int* __restrict__ offs, int* __restrict__ cursor,
                                                   int* __restrict__ adj, int E) {
    int e = blockIdx.x * blockDim.x + threadIdx.x;
    if (e >= E) return;
    const int c = dst[e];
    const int p = atomicAdd(&cursor[c], 1);
    adj[offs[c] + p] = src[e];
}

// ---------- W' = W_gcn @ W_lin, stored transposed ----------
__global__ __launch_bounds__(128) void wp_kernel(const float* __restrict__ Wg,
                                                 const float* __restrict__ Wl,
                                                 float* __restrict__ WpT) {
    int i = blockIdx.x;
    int j = threadIdx.x;
    float s = 0.f;
    for (int k = 0; k < DIM; ++k)
        s = fmaf(Wg[i * DIM + k], Wl[k * DIM + j], s);
    WpT[j * DIM + i] = s;
}

// ---------- h_s[n,:] = dinv[n] * (x[n,:] @ Wp^T) ----------
__global__ __launch_bounds__(256) void gemm_hs_kernel(const float* __restrict__ x,
                                                      const float* __restrict__ WpT,
                                                      const float* __restrict__ dinv,
                                                      float* __restrict__ h) {
    __shared__ float xs[BK * BM];    // [k][r] transposed, 8 KB
    __shared__ float ws[BK * DIM];   // [k][j], 32 KB
    const int tid  = threadIdx.x;
    const int brow = blockIdx.x * BM;
    const int c4   = (tid & 31) * 4;
    const int r4   = (tid >> 5) * 4;

    float acc[4][4];
#pragma unroll
    for (int i = 0; i < 4; ++i)
#pragma unroll
        for (int j = 0; j < 4; ++j) acc[i][j] = 0.f;

    for (int k0 = 0; k0 < DIM; k0 += BK) {
        {
            const int row = tid >> 3;
            const int kq  = (tid & 7) * 8;
            const float* xp = x + (size_t)(brow + row) * DIM + k0 + kq;
            const float4 a0 = *(const float4*)(xp);
            const float4 a1 = *(const float4*)(xp + 4);
            xs[(kq + 0) * BM + row] = a0.x;
            xs[(kq + 1) * BM + row] = a0.y;
            xs[(kq + 2) * BM + row] = a0.z;
            xs[(kq + 3) * BM + row] = a0.w;
            xs[(kq + 4) * BM + row] = a1.x;
            xs[(kq + 5) * BM + row] = a1.y;
            xs[(kq + 6) * BM + row] = a1.z;
            xs[(kq + 7) * BM + row] = a1.w;
        }
        {
            const float4* srcp = (const float4*)(WpT + (size_t)k0 * DIM);
            float4* dstp = (float4*)ws;
#pragma unroll
            for (int t = 0; t < 8; ++t) dstp[tid + t * 256] = srcp[tid + t * 256];
        }
        __syncthreads();

#pragma unroll 16
        for (int kk = 0; kk < BK; ++kk) {
            const float4 xv = *(const float4*)(xs + kk * BM + r4);
            const float4 wv = *(const float4*)(ws + kk * DIM + c4);
            const float xr[4] = {xv.x, xv.y, xv.z, xv.w};
            const float wr[4] = {wv.x, wv.y, wv.z, wv.w};
#pragma unroll
            for (int i = 0; i < 4; ++i)
#pragma unroll
                for (int j = 0; j < 4; ++j)
                    acc[i][j] = fmaf(xr[i], wr[j], acc[i][j]);
        }
        __syncthreads();
    }

#pragma unroll
    for (int i = 0; i < 4; ++i) {
        const int row = brow + r4 + i;
        const float dv = dinv[row];
        float4 o = make_float4(acc[i][0] * dv, acc[i][1] * dv, acc[i][2] * dv, acc[i][3] * dv);
        *(float4*)(h + (size_t)row * DIM + c4) = o;
    }
}

// ---------- gather: one wave per destination node ----------
// out[c,:] = dinv[c] * ( h_s[c,:] + sum_{s in CSR[c]} h_s[s,:] ) + b
__global__ __launch_bounds__(256) void gather_kernel(const float* __restrict__ h,
                                                     const int* __restrict__ adj,
                                                     const int* __restrict__ offs,
                                                     const int* __restrict__ degi,
                                                     const float* __restrict__ dinv,
                                                     const float* __restrict__ b,
                                                     float* __restrict__ out, int n) {
    const int wid = (blockIdx.x << 2) + (threadIdx.x >> 6);   // node id (4 waves/block)
    if (wid >= n) return;
    const int lane = threadIdx.x & 63;
    const float2* __restrict__ h2 = (const float2*)h;

    float2 acc = h2[(size_t)wid * 64 + lane];                 // self loop
    const int start = offs[wid];
    const int end   = start + degi[wid];
    int j = start;
    for (; j + 4 <= end; j += 4) {
        const int s0 = adj[j + 0];
        const int s1 = adj[j + 1];
        const int s2 = adj[j + 2];
        const int s3 = adj[j + 3];
        const float2 v0 = h2[(size_t)s0 * 64 + lane];
        const float2 v1 = h2[(size_t)s1 * 64 + lane];
        const float2 v2 = h2[(size_t)s2 * 64 + lane];
        const float2 v3 = h2[(size_t)s3 * 64 + lane];
        acc.x += (v0.x + v1.x) + (v2.x + v3.x);
        acc.y += (v0.y + v1.y) + (v2.y + v3.y);
    }
    for (; j < end; ++j) {
        const float2 v = h2[(size_t)adj[j] * 64 + lane];
        acc.x += v.x;
        acc.y += v.y;
    }
    const float dv = dinv[wid];
    const float2 bb = *(const float2*)(b + lane * 2);
    float2 o;
    o.x = dv * acc.x + bb.x;
    o.y = dv * acc.y + bb.y;
    ((float2*)out)[(size_t)wid * 64 + lane] = o;
}

extern "C" void kernel_launch(void* const* d_in, const int* in_sizes, int n_in,
                              void* d_out, int out_size, void* d_ws, size_t ws_size,
                              hipStream_t stream) {
    const float* x  = (const float*)d_in[0];   // fp32 [N,128]
    const int*   ei = (const int*)d_in[1];     // int32 flat [2,E]
    const float* Wl = (const float*)d_in[2];   // fp32 [128,128]
    const float* Wg = (const float*)d_in[3];   // fp32 [128,128]
    const float* bg = (const float*)d_in[4];   // fp32 [128]

    const int N = in_sizes[0] / DIM;      // 100000
    const int E = in_sizes[1] / 2;        // 1600000
    const int* srcIdx = ei;               // edge_index[0] = source
    const int* dstIdx = ei + E;           // edge_index[1] = target

    // workspace layout (byte offsets)
    char* wsb = (char*)d_ws;
    float* WpT    = (float*)(wsb + 0);            //  64 KB
    float* dinv   = (float*)(wsb + 65536);        // 400 KB
    int*   degi   = (int*)  (wsb + 465536);       // 400 KB
    int*   offs   = (int*)  (wsb + 865536);       // 400 KB
    int*   cursor = (int*)  (wsb + 1265536);      // 400 KB
    int*   blksum = (int*)  (wsb + 1665536);      // 512 B
    int*   adj    = (int*)  (wsb + 2097152);      // 6.4 MB
    float* h      = (float*)(wsb + 16777216);     // 51.2 MB
    const size_t needed = 16777216ull + (size_t)N * DIM * 4;
    if (ws_size < needed) return;

    hipMemsetAsync(degi,   0, (size_t)N * sizeof(int), stream);
    hipMemsetAsync(cursor, 0, (size_t)N * sizeof(int), stream);

    const int nb = (N + 1023) / 1024;     // 98 scan blocks (<=128)
    degi_kernel <<<(E + 255) / 256, 256, 0, stream>>>(dstIdx, degi, E);
    scan1_kernel<<<nb, 256, 0, stream>>>(degi, offs, blksum, N);
    scan2_kernel<<<1, 128, 0, stream>>>(blksum, nb);
    scan3_kernel<<<(N + 255) / 256, 256, 0, stream>>>(offs, blksum, N);
    dinv_kernel <<<(N + 255) / 256, 256, 0, stream>>>(degi, dinv, N);
    fill_kernel <<<(E + 255) / 256, 256, 0, stream>>>(srcIdx, dstIdx, offs, cursor, adj, E);
    wp_kernel   <<<DIM, DIM, 0, stream>>>(Wg, Wl, WpT);
    gemm_hs_kernel<<<N / BM, 256, 0, stream>>>(x, WpT, dinv, h);
    gather_kernel<<<(N + 3) / 4, 256, 0, stream>>>(h, adj, offs, degi, dinv, bg,
                                                   (float*)d_out, N);
}